// Round 1
// baseline (863.809 us; speedup 1.0000x reference)
//
#include <hip/hip_runtime.h>
#include <hip/hip_cooperative_groups.h>
#include <math.h>

// Problem constants
#define B 2
#define C 64
#define DD 64
#define HH 96
#define WW 96
#define HID 8
#define BC (B * C)                 // 128
#define SLICE (HH * WW)            // 9216 elements per d-slice
#define SLICE4 (SLICE / 4)         // 2304 float4 per d-slice
#define CHAN (DD * SLICE)          // 589824 elements per (b,c) channel
#define CHAN4 (CHAN / 4)           // 147456 float4 per channel
#define ROW4 (WW / 4)              // 24 float4 per row

#define NCHUNK 16                  // d-chunks per (b,c) channel
#define DPB (DD / NCHUNK)          // 4 d-slices per chunk
#define GRID_BLK 1024              // 64 channels x 16 chunks; each block does b=0 and b=1
#define ITERS (DPB * SLICE4 / 256) // 36 f4-iterations per (bc,chunk) task

// Workspace layout (floats): only partials; gates live in LDS in the fused path.
#define WS_PART 0                  // [0, 2048)
#define WS_GATE (BC * NCHUNK)      // [2048, 2176) — used by fallback path only

typedef float f4 __attribute__((ext_vector_type(4)));
namespace cg = cooperative_groups;

// ---------------------------------------------------------------------------
// Shared device helpers (emitted inline in both fused and fallback kernels)
// ---------------------------------------------------------------------------
__device__ __forceinline__ void compute_clsw(const float* __restrict__ dw_w,
                                             int c, int tid, float* w27) {
    // class per axis: 0 = pos==0 (taps {0,1}), 1 = interior (all), 2 = last ({1,2})
    if (tid < 27) {
        int cd = tid / 9, r = tid % 9, ch = r / 3, cw = r % 3;
        int kd0 = (cd == 2) ? 1 : 0, kd1 = (cd == 0) ? 1 : 2;
        int kh0 = (ch == 2) ? 1 : 0, kh1 = (ch == 0) ? 1 : 2;
        int kw0 = (cw == 2) ? 1 : 0, kw1 = (cw == 0) ? 1 : 2;
        float s = 0.f;
        for (int kd = kd0; kd <= kd1; ++kd)
            for (int kh = kh0; kh <= kh1; ++kh)
                for (int kw = kw0; kw <= kw1; ++kw)
                    s += dw_w[c * 27 + kd * 9 + kh * 3 + kw];
        w27[tid] = s;
    }
}

// Weighted reduce of one (bc, chunk) task: 4 contiguous d-slices, 36 f4/thread.
__device__ __forceinline__ float reduce_task(const float* __restrict__ x,
                                             const float* w27,
                                             int bc, int d0, int tid,
                                             int h0, int j0) {
    const f4* xb = (const f4*)x + (size_t)bc * CHAN4 + (size_t)d0 * SLICE4;
    float acc = 0.f;
    for (int sd = 0; sd < DPB; ++sd) {
        const int d = d0 + sd;
        const float* w9 = &w27[((d == 0) ? 0 : ((d == DD - 1) ? 2 : 1)) * 9];
        const f4* x4 = xb + (size_t)sd * SLICE4;
        int h = h0, j = j0;
        #pragma unroll
        for (int it = 0; it < SLICE4 / 256; ++it) {   // 9 iterations
            f4 v = x4[it * 256 + tid];
            int chc = (h == 0) ? 0 : ((h == HH - 1) ? 2 : 1);
            float wmid = w9[chc * 3 + 1];
            float w0 = (j == 0) ? w9[chc * 3 + 0] : wmid;
            float w3 = (j == ROW4 - 1) ? w9[chc * 3 + 2] : wmid;
            acc += v.x * w0 + (v.y + v.z) * wmid + v.w * w3;
            h += 10; j += 16;                          // advance by 256 = 10*24+16
            if (j >= ROW4) { j -= ROW4; h += 1; }
        }
    }
    return acc;
}

// ---------------------------------------------------------------------------
// Fused cooperative kernel: reduce -> grid sync -> gate (redundant) -> scale.
// Block b handles channel c = b>>4, d-chunk = b&15, for BOTH batches.
// ---------------------------------------------------------------------------
__global__ __launch_bounds__(256, 4) void fused_se(
        const float* __restrict__ x, const float* __restrict__ dw_w,
        const float* __restrict__ fc1_w, const float* __restrict__ fc1_b,
        const float* __restrict__ fc2_w, const float* __restrict__ fc2_b,
        float* __restrict__ out, float* __restrict__ ws) {
    const int tid   = threadIdx.x;
    const int c     = blockIdx.x >> 4;
    const int chunk = blockIdx.x & (NCHUNK - 1);
    const int d0    = chunk * DPB;

    __shared__ float w27[27];
    __shared__ float part[4];
    __shared__ float zsh[BC];
    __shared__ float hsh[B * HID];
    __shared__ float gsh[BC];

    compute_clsw(dw_w, c, tid, w27);
    __syncthreads();

    const int h0 = tid / ROW4;
    const int j0 = tid - h0 * ROW4;

    // ---- phase 1: weighted reduce (batch 0 then batch 1) ----
    for (int sel = 0; sel < 2; ++sel) {
        const int bc = sel * C + c;
        float acc = reduce_task(x, w27, bc, d0, tid, h0, j0);
        for (int off = 32; off > 0; off >>= 1)
            acc += __shfl_down(acc, off, 64);
        __syncthreads();                         // part[] reuse guard
        if ((tid & 63) == 0) part[tid >> 6] = acc;
        __syncthreads();
        if (tid == 0)
            ws[WS_PART + bc * NCHUNK + chunk] = part[0] + part[1] + part[2] + part[3];
    }

    // ---- phase 2: grid-wide barrier (device-scope fence + sync) ----
    __threadfence();
    cg::this_grid().sync();

    // ---- phase 3: every block redundantly computes all 128 gates (tiny) ----
    if (tid < BC) {
        float s0 = 0.f;
        #pragma unroll
        for (int p = 0; p < NCHUNK; ++p) s0 += ws[WS_PART + tid * NCHUNK + p];
        zsh[tid] = s0 * (1.0f / (float)CHAN);
    }
    __syncthreads();
    if (tid < B * HID) {
        int b = tid >> 3, j = tid & 7;
        float s = fc1_b[j];
        for (int cc = 0; cc < C; ++cc) s += fc1_w[j * C + cc] * zsh[b * C + cc];
        hsh[tid] = (s >= 0.f) ? s : 0.01f * s;   // LeakyReLU(0.01)
    }
    __syncthreads();
    if (tid < BC) {
        int b = tid >> 6, cc = tid & (C - 1);
        float s = fc2_b[cc];
        for (int j = 0; j < HID; ++j) s += fc2_w[cc * HID + j] * hsh[b * HID + j];
        gsh[tid] = 1.f / (1.f + expf(-s));
    }
    __syncthreads();

    // ---- phase 4: scale own chunks, batch-1 first and REVERSED so the most
    // recently cached L3 lines are re-read first. Cached loads for x (let L3
    // serve the second read); NT stores for out (never re-read, don't evict x).
    const f4* xp = (const f4*)x;
    f4* op = (f4*)out;
    for (int sel = 1; sel >= 0; --sel) {
        const int bc = sel * C + c;
        const float g = gsh[bc];
        const size_t base = (size_t)bc * CHAN4 + (size_t)d0 * SLICE4 + tid;
        #pragma unroll 6
        for (int it = ITERS - 1; it >= 0; --it) {
            size_t idx = base + (size_t)it * 256;
            f4 v = xp[idx];
            __builtin_nontemporal_store(v * g, &op[idx]);
        }
    }
}

// ---------------------------------------------------------------------------
// Fallback path (3 plain kernels) in case cooperative launch is rejected.
// ---------------------------------------------------------------------------
__global__ __launch_bounds__(256) void fb_reduce(const float* __restrict__ x,
                                                 const float* __restrict__ dw_w,
                                                 float* __restrict__ ws) {
    const int tid   = threadIdx.x;
    const int c     = blockIdx.x >> 4;
    const int chunk = blockIdx.x & (NCHUNK - 1);
    const int d0    = chunk * DPB;
    __shared__ float w27[27];
    __shared__ float part[4];
    compute_clsw(dw_w, c, tid, w27);
    __syncthreads();
    const int h0 = tid / ROW4;
    const int j0 = tid - h0 * ROW4;
    for (int sel = 0; sel < 2; ++sel) {
        const int bc = sel * C + c;
        float acc = reduce_task(x, w27, bc, d0, tid, h0, j0);
        for (int off = 32; off > 0; off >>= 1)
            acc += __shfl_down(acc, off, 64);
        __syncthreads();
        if ((tid & 63) == 0) part[tid >> 6] = acc;
        __syncthreads();
        if (tid == 0)
            ws[WS_PART + bc * NCHUNK + chunk] = part[0] + part[1] + part[2] + part[3];
    }
}

__global__ void fb_gate(const float* __restrict__ fc1_w, const float* __restrict__ fc1_b,
                        const float* __restrict__ fc2_w, const float* __restrict__ fc2_b,
                        float* __restrict__ ws) {
    __shared__ float zsh[BC];
    __shared__ float hsh[B * HID];
    int t = threadIdx.x;  // 0..127
    float s0 = 0.f;
    for (int p = 0; p < NCHUNK; ++p) s0 += ws[WS_PART + t * NCHUNK + p];
    zsh[t] = s0 * (1.0f / (float)CHAN);
    __syncthreads();
    if (t < B * HID) {
        int b = t >> 3, j = t & 7;
        float s = fc1_b[j];
        for (int cc = 0; cc < C; ++cc) s += fc1_w[j * C + cc] * zsh[b * C + cc];
        hsh[t] = (s >= 0.f) ? s : 0.01f * s;
    }
    __syncthreads();
    int b = t >> 6, cc = t & (C - 1);
    float s = fc2_b[cc];
    for (int j = 0; j < HID; ++j) s += fc2_w[cc * HID + j] * hsh[b * HID + j];
    ws[WS_GATE + t] = 1.f / (1.f + expf(-s));
}

__global__ __launch_bounds__(256) void fb_scale(const float* __restrict__ x,
                                                const float* __restrict__ ws,
                                                float* __restrict__ out) {
    const int tid   = threadIdx.x;
    const int c     = blockIdx.x >> 4;
    const int chunk = blockIdx.x & (NCHUNK - 1);
    const int d0    = chunk * DPB;
    const f4* xp = (const f4*)x;
    f4* op = (f4*)out;
    for (int sel = 1; sel >= 0; --sel) {
        const int bc = sel * C + c;
        const float g = ws[WS_GATE + bc];
        const size_t base = (size_t)bc * CHAN4 + (size_t)d0 * SLICE4 + tid;
        #pragma unroll 6
        for (int it = ITERS - 1; it >= 0; --it) {
            size_t idx = base + (size_t)it * 256;
            f4 v = xp[idx];
            __builtin_nontemporal_store(v * g, &op[idx]);
        }
    }
}

// ---------------------------------------------------------------------------
extern "C" void kernel_launch(void* const* d_in, const int* in_sizes, int n_in,
                              void* d_out, int out_size, void* d_ws, size_t ws_size,
                              hipStream_t stream) {
    const float* x     = (const float*)d_in[0];
    const float* dw_w  = (const float*)d_in[1];
    const float* fc1_w = (const float*)d_in[2];
    const float* fc1_b = (const float*)d_in[3];
    const float* fc2_w = (const float*)d_in[4];
    const float* fc2_b = (const float*)d_in[5];
    float* out = (float*)d_out;
    float* ws  = (float*)d_ws;

    void* args[] = {(void*)&x, (void*)&dw_w, (void*)&fc1_w, (void*)&fc1_b,
                    (void*)&fc2_w, (void*)&fc2_b, (void*)&out, (void*)&ws};
    hipError_t e = hipLaunchCooperativeKernel(
        reinterpret_cast<void*>(fused_se), dim3(GRID_BLK), dim3(256), args, 0, stream);
    if (e != hipSuccess) {
        // Cooperative rejected (e.g. unsupported in this capture mode): plain path.
        fb_reduce<<<dim3(GRID_BLK), dim3(256), 0, stream>>>(x, dw_w, ws);
        fb_gate<<<dim3(1), dim3(BC), 0, stream>>>(fc1_w, fc1_b, fc2_w, fc2_b, ws);
        fb_scale<<<dim3(GRID_BLK), dim3(256), 0, stream>>>(x, ws, out);
    }
}

// Round 2
// 557.999 us; speedup vs baseline: 1.5480x; 1.5480x over previous
//
#include <hip/hip_runtime.h>
#include <math.h>

// Problem constants
#define B 2
#define C 64
#define DD 64
#define HH 96
#define WW 96
#define HID 8
#define BC (B * C)                 // 128
#define SLICE (HH * WW)            // 9216 elements per d-slice
#define SLICE4 (SLICE / 4)         // 2304 float4 per d-slice
#define CHAN (DD * SLICE)          // 589824 elements per (b,c) channel
#define CHAN4 (CHAN / 4)           // 147456 float4 per channel
#define ROW4 (WW / 4)              // 24 float4 per row

#define RED_BX 16                  // reduce blocks along d per (b,c)
#define DPB (DD / RED_BX)          // 4 d-slices per reduce block
#define SC_F4 16                   // float4 per thread in scale kernel
#define SC_BX (CHAN4 / (256 * SC_F4))  // 36 scale blocks per (b,c)

// Workspace layout (floats):
#define WS_PART 0                  // [0, 2048): per-block reduce partials
#define WS_GATE (BC * RED_BX)     // [2048, 2176): per-(b,c) gate

typedef float f4 __attribute__((ext_vector_type(4)));

// ---------------------------------------------------------------------------
// Per-channel 27 boundary-class effective weight sums, computed in-block.
// class per axis: 0 = pos==0 (taps {0,1}), 1 = interior (all), 2 = last ({1,2})
__device__ __forceinline__ void compute_clsw(const float* __restrict__ dw_w,
                                             int c, int tid, float* w27) {
    if (tid < 27) {
        int cd = tid / 9, r = tid % 9, ch = r / 3, cw = r % 3;
        int kd0 = (cd == 2) ? 1 : 0, kd1 = (cd == 0) ? 1 : 2;
        int kh0 = (ch == 2) ? 1 : 0, kh1 = (ch == 0) ? 1 : 2;
        int kw0 = (cw == 2) ? 1 : 0, kw1 = (cw == 0) ? 1 : 2;
        float s = 0.f;
        for (int kd = kd0; kd <= kd1; ++kd)
            for (int kh = kh0; kh <= kh1; ++kh)
                for (int kw = kw0; kw <= kw1; ++kw)
                    s += dw_w[c * 27 + kd * 9 + kh * 3 + kw];
        w27[tid] = s;
    }
}

// ---------------------------------------------------------------------------
// Kernel 1: weighted reduction of x -> per-block partials (atomic-free).
// grid = (RED_BX, BC); each block reduces DPB d-slices of one (b,c) channel.
// Plain (cached) loads: reads populate L2/L3 so the scale pass can reuse them.
__global__ __launch_bounds__(256) void reduce_kernel(const float* __restrict__ x,
                                                     const float* __restrict__ dw_w,
                                                     float* __restrict__ ws) {
    const int bc = blockIdx.y;
    const int c  = bc & (C - 1);
    const int d0 = blockIdx.x * DPB;
    const int tid = threadIdx.x;

    __shared__ float w27[27];
    __shared__ float part[4];

    compute_clsw(dw_w, c, tid, w27);
    __syncthreads();

    const f4* xb = (const f4*)x + (size_t)bc * CHAN4;
    float acc = 0.f;

    const int h0 = tid / ROW4;           // one div per thread, outside the loop
    const int j0 = tid - h0 * ROW4;

    for (int sd = 0; sd < DPB; ++sd) {
        const int d  = d0 + sd;
        const float* w9 = &w27[((d == 0) ? 0 : ((d == DD - 1) ? 2 : 1)) * 9];
        const f4* x4 = xb + (size_t)d * SLICE4;
        int h = h0, j = j0;
        #pragma unroll
        for (int it = 0; it < SLICE4 / 256; ++it) {   // 9 iterations
            f4 v = x4[it * 256 + tid];
            int chc = (h == 0) ? 0 : ((h == HH - 1) ? 2 : 1);
            float wmid = w9[chc * 3 + 1];
            float w0 = (j == 0) ? w9[chc * 3 + 0] : wmid;
            float w3 = (j == ROW4 - 1) ? w9[chc * 3 + 2] : wmid;
            acc += v.x * w0 + (v.y + v.z) * wmid + v.w * w3;
            // advance linear index by 256 = 10*24 + 16
            h += 10; j += 16;
            if (j >= ROW4) { j -= ROW4; h += 1; }
        }
    }

    for (int off = 32; off > 0; off >>= 1)
        acc += __shfl_down(acc, off, 64);
    if ((tid & 63) == 0) part[tid >> 6] = acc;
    __syncthreads();
    if (tid == 0)
        ws[WS_PART + bc * RED_BX + blockIdx.x] = part[0] + part[1] + part[2] + part[3];
}

// ---------------------------------------------------------------------------
// Kernel 2: sum partials -> z -> SE MLP -> sigmoid gate. 1 block, 128 threads.
__global__ void gate_kernel(const float* __restrict__ fc1_w, const float* __restrict__ fc1_b,
                            const float* __restrict__ fc2_w, const float* __restrict__ fc2_b,
                            float* __restrict__ ws) {
    __shared__ float zsh[BC];
    __shared__ float hsh[B * HID];
    int t = threadIdx.x;  // 0..127
    float s0 = 0.f;
    for (int p = 0; p < RED_BX; ++p) s0 += ws[WS_PART + t * RED_BX + p];
    zsh[t] = s0 * (1.0f / (float)CHAN);
    __syncthreads();
    if (t < B * HID) {
        int b = t >> 3, j = t & 7;
        float s = fc1_b[j];
        for (int cc = 0; cc < C; ++cc) s += fc1_w[j * C + cc] * zsh[b * C + cc];
        hsh[t] = (s >= 0.f) ? s : 0.01f * s;  // LeakyReLU(0.01)
    }
    __syncthreads();
    int b = t >> 6, cc = t & (C - 1);
    float s = fc2_b[cc];
    for (int j = 0; j < HID; ++j) s += fc2_w[cc * HID + j] * hsh[b * HID + j];
    ws[WS_GATE + t] = 1.f / (1.f + expf(-s));
}

// ---------------------------------------------------------------------------
// Kernel 3: out = x * gate[b,c]. grid = (SC_BX, BC), SC_F4 float4 per thread.
// Plain cached loads AND stores (NT stores caused 1.78x write amplification:
// WRITE_SIZE 536 MB vs 302 MB of output — sub-line HBM writes). Block mapping
// is REVERSED so the earliest scale blocks re-read the tail of x, which the
// reduce pass touched last and is still resident in the 256 MiB L3.
__global__ __launch_bounds__(256) void scale_kernel(const float* __restrict__ x,
                                                    const float* __restrict__ ws,
                                                    float* __restrict__ out) {
    const int bc = (BC - 1) - blockIdx.y;
    const int bx = (SC_BX - 1) - blockIdx.x;
    const float g = ws[WS_GATE + bc];
    const size_t base = (size_t)bc * CHAN4 + (size_t)bx * (256 * SC_F4) + threadIdx.x;
    const f4* xp = (const f4*)x;
    f4* op = (f4*)out;
    #pragma unroll
    for (int k = 0; k < SC_F4; ++k) {
        size_t idx = base + (size_t)k * 256;
        op[idx] = xp[idx] * g;
    }
}

// ---------------------------------------------------------------------------
extern "C" void kernel_launch(void* const* d_in, const int* in_sizes, int n_in,
                              void* d_out, int out_size, void* d_ws, size_t ws_size,
                              hipStream_t stream) {
    const float* x     = (const float*)d_in[0];
    const float* dw_w  = (const float*)d_in[1];
    const float* fc1_w = (const float*)d_in[2];
    const float* fc1_b = (const float*)d_in[3];
    const float* fc2_w = (const float*)d_in[4];
    const float* fc2_b = (const float*)d_in[5];
    float* out = (float*)d_out;
    float* ws  = (float*)d_ws;

    reduce_kernel<<<dim3(RED_BX, BC), dim3(256), 0, stream>>>(x, dw_w, ws);
    gate_kernel<<<dim3(1), dim3(BC), 0, stream>>>(fc1_w, fc1_b, fc2_w, fc2_b, ws);
    scale_kernel<<<dim3(SC_BX, BC), dim3(256), 0, stream>>>(x, ws, out);
}

// Round 3
// 557.521 us; speedup vs baseline: 1.5494x; 1.0009x over previous
//
#include <hip/hip_runtime.h>
#include <math.h>

// Problem constants
#define B 2
#define C 64
#define DD 64
#define HH 96
#define WW 96
#define HID 8
#define BC (B * C)                 // 128
#define SLICE (HH * WW)            // 9216 elements per d-slice
#define SLICE4 (SLICE / 4)         // 2304 float4 per d-slice
#define CHAN (DD * SLICE)          // 589824 elements per (b,c) channel
#define CHAN4 (CHAN / 4)           // 147456 float4 per channel
#define ROW4 (WW / 4)              // 24 float4 per row
#define SEGS (SLICE4 / 256)        // 9 segments of 256 f4 per slice

#define RED_BX 16                  // reduce blocks along d per (b,c)
#define DPB (DD / RED_BX)          // 4 d-slices per reduce block
#define SC_F4 16                   // float4 per thread in scale kernel
#define SC_BX (CHAN4 / (256 * SC_F4))  // 36 scale blocks per (b,c)

// Workspace layout (floats):
#define WS_PART 0                  // [0, 2048): per-block reduce partials

typedef float f4 __attribute__((ext_vector_type(4)));

// ---------------------------------------------------------------------------
// Per-channel 27 boundary-class effective weight sums (in-block, 27 lanes).
// class per axis: 0 = pos==0 (taps {0,1}), 1 = interior (all), 2 = last ({1,2})
__device__ __forceinline__ void compute_clsw(const float* __restrict__ dw_w,
                                             int c, int tid, float* w27) {
    if (tid < 27) {
        int cd = tid / 9, r = tid % 9, ch = r / 3, cw = r % 3;
        int kd0 = (cd == 2) ? 1 : 0, kd1 = (cd == 0) ? 1 : 2;
        int kh0 = (ch == 2) ? 1 : 0, kh1 = (ch == 0) ? 1 : 2;
        int kw0 = (cw == 2) ? 1 : 0, kw1 = (cw == 0) ? 1 : 2;
        float s = 0.f;
        for (int kd = kd0; kd <= kd1; ++kd)
            for (int kh = kh0; kh <= kh1; ++kh)
                for (int kw = kw0; kw <= kw1; ++kw)
                    s += dw_w[c * 27 + kd * 9 + kh * 3 + kw];
        w27[tid] = s;
    }
}

// ---------------------------------------------------------------------------
// Kernel 1: weighted reduction. grid = (RED_BX, BC).
// Hot loop contains ONLY global_load_dwordx4 + FMAs: all per-position weight
// triples are hoisted to registers in a prologue (27 VGPRs), 4 independent
// accumulators (one per d-slice) maximize loads in flight. The 2 boundary-d
// chunks per channel (d=0 / d=63 slices) take a generic slow path.
__global__ __launch_bounds__(256) void reduce_kernel(const float* __restrict__ x,
                                                     const float* __restrict__ dw_w,
                                                     float* __restrict__ ws) {
    const int bc    = blockIdx.y;
    const int c     = bc & (C - 1);
    const int chunk = blockIdx.x;
    const int d0    = chunk * DPB;
    const int tid   = threadIdx.x;

    __shared__ float w27[27];
    __shared__ float part[4];
    compute_clsw(dw_w, c, tid, w27);
    __syncthreads();

    const f4* xb = (const f4*)x + (size_t)bc * CHAN4 + (size_t)d0 * SLICE4;
    float acc[DPB] = {0.f, 0.f, 0.f, 0.f};

    if (chunk != 0 && chunk != RED_BX - 1) {
        // ---- fast path: all 4 slices are d-interior (cd = 1) ----
        // prologue: per-segment weight triple in registers (LDS reads done here)
        float w0r[SEGS], wmr[SEGS], w3r[SEGS];
        #pragma unroll
        for (int s = 0; s < SEGS; ++s) {
            int p = s * 256 + tid;
            int h = p / ROW4;
            int j = p - h * ROW4;
            int chc = (h == 0) ? 0 : ((h == HH - 1) ? 2 : 1);
            float wm = w27[9 + chc * 3 + 1];
            wmr[s] = wm;
            w0r[s] = (j == 0)        ? w27[9 + chc * 3 + 0] : wm;
            w3r[s] = (j == ROW4 - 1) ? w27[9 + chc * 3 + 2] : wm;
        }
        // hot loop: 36 independent loads, no LDS, no branches
        #pragma unroll
        for (int s = 0; s < SEGS; ++s) {
            const int p = s * 256 + tid;
            #pragma unroll
            for (int sd = 0; sd < DPB; ++sd) {
                f4 v = xb[(size_t)sd * SLICE4 + p];
                acc[sd] += v.x * w0r[s] + (v.y + v.z) * wmr[s] + v.w * w3r[s];
            }
        }
    } else {
        // ---- generic path: per-slice d-class (only 256 of 2048 blocks) ----
        #pragma unroll
        for (int sd = 0; sd < DPB; ++sd) {
            const int d  = d0 + sd;
            const int cd = (d == 0) ? 0 : ((d == DD - 1) ? 2 : 1);
            #pragma unroll
            for (int s = 0; s < SEGS; ++s) {
                int p = s * 256 + tid;
                int h = p / ROW4;
                int j = p - h * ROW4;
                int chc = (h == 0) ? 0 : ((h == HH - 1) ? 2 : 1);
                float wm = w27[cd * 9 + chc * 3 + 1];
                float w0 = (j == 0)        ? w27[cd * 9 + chc * 3 + 0] : wm;
                float w3 = (j == ROW4 - 1) ? w27[cd * 9 + chc * 3 + 2] : wm;
                f4 v = xb[(size_t)sd * SLICE4 + p];
                acc[sd] += v.x * w0 + (v.y + v.z) * wm + v.w * w3;
            }
        }
    }

    float a = (acc[0] + acc[1]) + (acc[2] + acc[3]);
    for (int off = 32; off > 0; off >>= 1)
        a += __shfl_down(a, off, 64);
    if ((tid & 63) == 0) part[tid >> 6] = a;
    __syncthreads();
    if (tid == 0)
        ws[WS_PART + bc * RED_BX + chunk] = (part[0] + part[1]) + (part[2] + part[3]);
}

// ---------------------------------------------------------------------------
// Kernel 2: gate (computed redundantly per block — removes the 1-block
// gate_kernel and its full-device drain/refill bubble) + scale stream.
// grid = (SC_BX, BC). Preamble is ~1 µs and overlaps across resident blocks.
__global__ __launch_bounds__(256) void scale_kernel(
        const float* __restrict__ x,
        const float* __restrict__ fc1_w, const float* __restrict__ fc1_b,
        const float* __restrict__ fc2_w, const float* __restrict__ fc2_b,
        const float* __restrict__ ws, float* __restrict__ out) {
    const int bc = blockIdx.y;
    const int b  = bc >> 6;
    const int c  = bc & (C - 1);
    const int t  = threadIdx.x;

    __shared__ float zsh[C];
    __shared__ float hsh[HID];
    __shared__ float gsh;

    // z for our batch b (64 channel means)
    if (t < C) {
        float s0 = 0.f;
        #pragma unroll
        for (int p = 0; p < RED_BX; ++p)
            s0 += ws[WS_PART + (b * C + t) * RED_BX + p];
        zsh[t] = s0 * (1.0f / (float)CHAN);
    }
    __syncthreads();
    if (t < HID) {
        float s = fc1_b[t];
        #pragma unroll
        for (int cc = 0; cc < C; ++cc) s += fc1_w[t * C + cc] * zsh[cc];
        hsh[t] = (s >= 0.f) ? s : 0.01f * s;   // LeakyReLU(0.01)
    }
    __syncthreads();
    if (t == 0) {
        float s = fc2_b[c];
        #pragma unroll
        for (int j = 0; j < HID; ++j) s += fc2_w[c * HID + j] * hsh[j];
        gsh = 1.f / (1.f + expf(-s));
    }
    __syncthreads();
    const float g = gsh;

    const size_t base = (size_t)bc * CHAN4 + (size_t)blockIdx.x * (256 * SC_F4) + t;
    const f4* xp = (const f4*)x;
    f4* op = (f4*)out;
    #pragma unroll
    for (int k = 0; k < SC_F4; ++k) {
        size_t idx = base + (size_t)k * 256;
        op[idx] = xp[idx] * g;   // plain cached load + store
    }
}

// ---------------------------------------------------------------------------
extern "C" void kernel_launch(void* const* d_in, const int* in_sizes, int n_in,
                              void* d_out, int out_size, void* d_ws, size_t ws_size,
                              hipStream_t stream) {
    const float* x     = (const float*)d_in[0];
    const float* dw_w  = (const float*)d_in[1];
    const float* fc1_w = (const float*)d_in[2];
    const float* fc1_b = (const float*)d_in[3];
    const float* fc2_w = (const float*)d_in[4];
    const float* fc2_b = (const float*)d_in[5];
    float* out = (float*)d_out;
    float* ws  = (float*)d_ws;

    reduce_kernel<<<dim3(RED_BX, BC), dim3(256), 0, stream>>>(x, dw_w, ws);
    scale_kernel<<<dim3(SC_BX, BC), dim3(256), 0, stream>>>(x, fc1_w, fc1_b,
                                                            fc2_w, fc2_b, ws, out);
}